// Round 1
// baseline (273.694 us; speedup 1.0000x reference)
//
#include <hip/hip_runtime.h>
#include <hip/hip_bf16.h>
#include <math.h>

#define NN 2304      // H*W = 48*48
#define ROWSZ 4608   // B*N
#define SZ (ROWSZ*256)

typedef __attribute__((ext_vector_type(8))) short short8;
typedef __attribute__((ext_vector_type(4))) float f32x4;

__device__ __forceinline__ float bf2f(unsigned short u) {
    return __uint_as_float(((unsigned int)u) << 16);
}
__device__ __forceinline__ unsigned short f2bf(float f) {
    unsigned int u = __float_as_uint(f);
    u += 0x7FFFu + ((u >> 16) & 1u);   // round-to-nearest-even
    return (unsigned short)(u >> 16);
}
__device__ __forceinline__ unsigned int pack_bf2(float a, float b) {
    return (unsigned int)f2bf(a) | ((unsigned int)f2bf(b) << 16);
}

template<int F32>
__device__ __forceinline__ float ldin(const void* p, int i) {
    if constexpr (F32) return ((const float*)p)[i];
    else return bf2f(((const unsigned short*)p)[i]);
}

// ---------------- dtype detector -------------------------------------------
__global__ void detect_kernel(const unsigned int* __restrict__ x, int* __restrict__ flag) {
    int t = threadIdx.x;
    int cnt = 0;
    for (int i = t; i < 256; i += 64) {
        unsigned int e = (x[i] >> 7) & 0xFFu;
        cnt += (e < 87u || e > 167u) ? 1 : 0;
    }
    #pragma unroll
    for (int o = 32; o; o >>= 1) cnt += __shfl_down(cnt, o);
    if (t == 0) *flag = (cnt >= 32) ? 1 : 0;
}

// ---------------- QKV projection + fused RoPE + k-scaling + vT -------------
// grid (288,3): 16 rows/block, blockIdx.y selects matrix {q,k,v}
template<int F32>
__device__ __forceinline__ void qkv_body(
    const void* __restrict__ x,
    const void* __restrict__ Wq, const void* __restrict__ bq,
    const void* __restrict__ Wk, const void* __restrict__ bk,
    const void* __restrict__ Wv, const void* __restrict__ bv,
    unsigned short* __restrict__ q, unsigned short* __restrict__ k,
    unsigned short* __restrict__ v, unsigned short* __restrict__ vT,
    float* __restrict__ xs)
{
    const int t = threadIdx.x;
    const int by = blockIdx.y;
    const int row0 = blockIdx.x * 16;
    #pragma unroll
    for (int pass = 0; pass < 2; ++pass) {
        int e = pass*2048 + t*8;
        if constexpr (F32) {
            const float* xp = (const float*)x + row0*256 + e;
            float4 a0 = *reinterpret_cast<const float4*>(xp);
            float4 a1 = *reinterpret_cast<const float4*>(xp + 4);
            *reinterpret_cast<float4*>(&xs[e])   = a0;
            *reinterpret_cast<float4*>(&xs[e+4]) = a1;
        } else {
            const unsigned short* xp = (const unsigned short*)x + row0*256 + e;
            uint4 raw = *reinterpret_cast<const uint4*>(xp);
            const unsigned short* us = reinterpret_cast<const unsigned short*>(&raw);
            #pragma unroll
            for (int j = 0; j < 8; ++j) xs[e + j] = bf2f(us[j]);
        }
    }
    __syncthreads();
    const void* Wsel = (by == 0) ? Wq : (by == 1) ? Wk : Wv;
    const void* bsel = (by == 0) ? bq : (by == 1) ? bk : bv;
    float a[16];
    const float bv0 = ldin<F32>(bsel, t);
    #pragma unroll
    for (int r = 0; r < 16; ++r) a[r] = bv0;
    for (int i0 = 0; i0 < 256; i0 += 4) {
        float w0 = ldin<F32>(Wsel, (i0+0)*256 + t);
        float w1 = ldin<F32>(Wsel, (i0+1)*256 + t);
        float w2 = ldin<F32>(Wsel, (i0+2)*256 + t);
        float w3 = ldin<F32>(Wsel, (i0+3)*256 + t);
        #pragma unroll
        for (int r = 0; r < 16; ++r) {
            float4 xv = *reinterpret_cast<const float4*>(&xs[r*256 + i0]);
            a[r] = fmaf(xv.w,w3, fmaf(xv.z,w2, fmaf(xv.y,w1, fmaf(xv.x,w0, a[r]))));
        }
    }
    if (by == 2) {
        // v row-major + vT [bh][d][n]
        const int b = (row0 >= NN) ? 1 : 0;
        const int n0 = row0 - b*NN;
        const int h = t >> 5, d = t & 31;
        unsigned int vp[8];
        #pragma unroll
        for (int r = 0; r < 16; ++r) v[(row0 + r)*256 + t] = f2bf(a[r]);
        #pragma unroll
        for (int r = 0; r < 8; ++r) vp[r] = pack_bf2(a[2*r], a[2*r+1]);
        unsigned short* vt = vT + ((size_t)(b*8 + h)*32 + d)*NN + n0;
        *reinterpret_cast<uint4*>(vt)     = make_uint4(vp[0], vp[1], vp[2], vp[3]);
        *reinterpret_cast<uint4*>(vt + 8) = make_uint4(vp[4], vp[5], vp[6], vp[7]);
    } else {
        // RoPE: column t -> pair j=(t&31)>>1
        const float scaling = 0.17677669529663687f;  // 32^-0.5
        const int j = (t & 31) >> 1;
        const float ang = exp2f((float)j * (-0.8858474919699633f)); // 10000^(-j/15)
        const bool odd = t & 1;
        unsigned short* dst = (by == 0) ? q : k;
        const float mul = (by == 0) ? 1.0f : scaling;
        #pragma unroll
        for (int r = 0; r < 16; ++r) {
            int bn = row0 + r;
            int n = bn >= NN ? bn - NN : bn;
            float sv, cv;
            sincosf((float)n * ang, &sv, &cv);
            float ap = __shfl_xor(a[r], 1);
            float val = odd ? fmaf(a[r], cv, ap*sv) : fmaf(a[r], cv, -ap*sv);
            dst[bn*256 + t] = f2bf(val * mul);
        }
    }
}

__global__ __launch_bounds__(256) void qkv_kernel(
    const void* __restrict__ x,
    const void* __restrict__ Wq, const void* __restrict__ bq,
    const void* __restrict__ Wk, const void* __restrict__ bk,
    const void* __restrict__ Wv, const void* __restrict__ bv,
    const int* __restrict__ flag,
    unsigned short* __restrict__ q, unsigned short* __restrict__ k,
    unsigned short* __restrict__ v, unsigned short* __restrict__ vT)
{
    __shared__ float xs[16*256];
    if (*flag) qkv_body<1>(x, Wq, bq, Wk, bk, Wv, bv, q, k, v, vT, xs);
    else       qkv_body<0>(x, Wq, bq, Wk, bk, Wv, bv, q, k, v, vT, xs);
}

// ---------------- depthwise 5x5 SAME conv on v (+ bias) --------------------
template<int F32>
__device__ __forceinline__ void lepe_body(const unsigned short* __restrict__ v,
    const void* __restrict__ w, const void* __restrict__ wb,
    unsigned short* __restrict__ lepe)
{
    int c = threadIdx.x;
    int pos = blockIdx.x;                // b*2304 + y*48 + x
    int b  = pos >= NN ? 1 : 0;
    int yx = pos - b*NN;
    int y  = (yx*21846) >> 20;           // yx/48 exact
    int xx = yx - y*48;
    float acc = ldin<F32>(wb, c);
    #pragma unroll
    for (int ky = 0; ky < 5; ++ky) {
        int yy = y + ky - 2;
        if ((unsigned)yy >= 48u) continue;
        #pragma unroll
        for (int kx = 0; kx < 5; ++kx) {
            int xc = xx + kx - 2;
            if ((unsigned)xc >= 48u) continue;
            acc = fmaf(bf2f(v[((b*NN + yy*48 + xc)<<8) + c]), ldin<F32>(w, c*25 + ky*5 + kx), acc);
        }
    }
    lepe[(pos<<8) + c] = f2bf(acc);
}

__global__ __launch_bounds__(256) void lepe_kernel(const unsigned short* __restrict__ v,
    const void* __restrict__ w, const void* __restrict__ wb,
    const int* __restrict__ flag, unsigned short* __restrict__ lepe)
{
    if (*flag) lepe_body<1>(v, w, wb, lepe);
    else       lepe_body<0>(v, w, wb, lepe);
}

// ---------------- MFMA flash attention with decay mask ---------------------
// grid (36,16), 256 thr = 4 independent waves; wave w: 16 q-rows; chunk = 64 kpos.
// No LDS staging of K/Vt (both L2-resident per bh: 147KB each) -> zero barriers.
// Fixed-max softmax (scores bounded ~1, mask <= 0): no online max/rescale; l
// accumulated per-lane, reduced once after the loop.
// S^T tiles: A=K (m=kpos), B=Q^T (n=q); PV: O^T = Vt * P^T.
__global__ __launch_bounds__(256) void attn_kernel(
    const unsigned short* __restrict__ q, const unsigned short* __restrict__ k,
    const unsigned short* __restrict__ vT, unsigned short* __restrict__ o)
{
    __shared__ char smem[8192];          // per-wave P scratch only
    const int t = threadIdx.x;
    const int w = t >> 6, lane = t & 63;
    const int q16 = lane & 15, quad = lane >> 4;
    char* PsB = smem + w*2048;           // frag-ordered P (2*1024B)
    const int bh = blockIdx.y, b = bh >> 3, h = bh & 7;
    const int q0 = blockIdx.x*64 + w*16;
    const int nq = q0 + q16;
    const int yq = (nq*21846) >> 20, xq = nq - yq*48;
    const float decay = logf(1.0f - exp2f(-1.0f - 0.375f*(float)h));
    short8 qfrag = *reinterpret_cast<const short8*>(q + ((size_t)(b*NN + nq))*256 + h*32 + quad*8);
    f32x4 acc0 = {0.f,0.f,0.f,0.f}, acc1 = {0.f,0.f,0.f,0.f};
    const f32x4 zero = {0.f,0.f,0.f,0.f};
    float lacc = 0.0f;
    // lane-fixed operand pointers
    const unsigned short* kptr  = k  + (size_t)(b*NN)*256 + h*32 + (size_t)q16*256 + quad*8;
    const unsigned short* vptr0 = vT + (size_t)bh*32*NN + (size_t)q16*NN + quad*8;
    const unsigned short* vptr1 = vptr0 + (size_t)16*NN;
    const int psW = q16*16 + (quad & 1)*8;    // P write base within group
    const int qsh = quad >> 1;

    // prologue: load chunk 0 operands
    short8 kf[4], vf[4];
    #pragma unroll
    for (int tt = 0; tt < 4; ++tt)
        kf[tt] = *reinterpret_cast<const short8*>(kptr + tt*16*256);
    #pragma unroll
    for (int kh = 0; kh < 2; ++kh) {
        vf[kh*2]   = *reinterpret_cast<const short8*>(vptr0 + kh*32);
        vf[kh*2+1] = *reinterpret_cast<const short8*>(vptr1 + kh*32);
    }

    for (int kt = 0; kt < 36; ++kt) {
        // prefetch next chunk operands (clamped; last iter re-loads harmlessly)
        const int ktn = (kt + 1 < 36) ? kt + 1 : 35;
        short8 nkf[4], nvf[4];
        #pragma unroll
        for (int tt = 0; tt < 4; ++tt)
            nkf[tt] = *reinterpret_cast<const short8*>(kptr + (ktn*64 + tt*16)*256);
        #pragma unroll
        for (int kh = 0; kh < 2; ++kh) {
            nvf[kh*2]   = *reinterpret_cast<const short8*>(vptr0 + ktn*64 + kh*32);
            nvf[kh*2+1] = *reinterpret_cast<const short8*>(vptr1 + ktn*64 + kh*32);
        }
        // QK^T: 4 S^T tiles of [16 kpos x 16 q]
        f32x4 st[4];
        #pragma unroll
        for (int tt = 0; tt < 4; ++tt)
            st[tt] = __builtin_amdgcn_mfma_f32_16x16x32_bf16(kf[tt], qfrag, zero, 0, 0, 0);
        // decay mask + exp (fixed max = 0), pack to bf16 pairs
        unsigned int pk[8];
        float lsum = 0.0f;
        #pragma unroll
        for (int tt = 0; tt < 4; ++tt) {
            float p[4];
            #pragma unroll
            for (int r = 0; r < 4; ++r) {
                int kpos = kt*64 + tt*16 + quad*4 + r;
                int yk = (kpos*21846) >> 20;
                int xk = kpos - yk*48;
                int dist = __usad((unsigned)yq, (unsigned)yk, __usad((unsigned)xq, (unsigned)xk, 0u));
                p[r] = __expf(fmaf(decay, (float)dist, st[tt][r]));
                lsum += p[r];
            }
            pk[tt*2]   = __builtin_amdgcn_perm(__float_as_uint(p[1]), __float_as_uint(p[0]), 0x07060302);
            pk[tt*2+1] = __builtin_amdgcn_perm(__float_as_uint(p[3]), __float_as_uint(p[2]), 0x07060302);
        }
        lacc += lsum;
        // P -> LDS (frag order, per-wave region, wave-internal ordering only)
        #pragma unroll
        for (int tt = 0; tt < 4; ++tt) {
            uint2 pp; pp.x = pk[tt*2]; pp.y = pk[tt*2+1];
            *reinterpret_cast<uint2*>(PsB + (tt >> 1)*1024 + (((tt*2) + qsh) & 3)*256 + psW) = pp;
        }
        // PV: O^T += Vt * P^T  (two 32-kpos steps, two 16-d tiles)
        #pragma unroll
        for (int kh = 0; kh < 2; ++kh) {
            short8 pf = *reinterpret_cast<const short8*>(PsB + kh*1024 + lane*16);
            acc0 = __builtin_amdgcn_mfma_f32_16x16x32_bf16(vf[kh*2],   pf, acc0, 0, 0, 0);
            acc1 = __builtin_amdgcn_mfma_f32_16x16x32_bf16(vf[kh*2+1], pf, acc1, 0, 0, 0);
        }
        // rotate prefetch registers
        #pragma unroll
        for (int i = 0; i < 4; ++i) { kf[i] = nkf[i]; vf[i] = nvf[i]; }
    }
    // deferred l reduction across quads
    lacc += __shfl_xor(lacc, 16);
    lacc += __shfl_xor(lacc, 32);
    float invl = 1.0f / lacc;
    // lane holds O^T[d = half*16 + quad*4 + r][q = nq]
    unsigned short* orow = o + ((size_t)(b*NN + nq))*256 + h*32;
    uint2 w0, w1;
    w0.x = pack_bf2(acc0[0]*invl, acc0[1]*invl);
    w0.y = pack_bf2(acc0[2]*invl, acc0[3]*invl);
    w1.x = pack_bf2(acc1[0]*invl, acc1[1]*invl);
    w1.y = pack_bf2(acc1[2]*invl, acc1[3]*invl);
    *reinterpret_cast<uint2*>(orow + quad*4)      = w0;
    *reinterpret_cast<uint2*>(orow + 16 + quad*4) = w1;
}

// ---------------- (attn_out + lepe) @ Wo + bo -> out -----------------------
// grid 576: 8 rows/block
template<int F32>
__device__ __forceinline__ void out_body(
    const unsigned short* __restrict__ o, const unsigned short* __restrict__ lp,
    const void* __restrict__ Wo, const void* __restrict__ bo,
    void* __restrict__ out, float* __restrict__ as)
{
    const int t = threadIdx.x;
    const int row0 = blockIdx.x * 8;
    {
        int e = t*8;
        uint4 ua = *reinterpret_cast<const uint4*>(o  + row0*256 + e);
        uint4 ub = *reinterpret_cast<const uint4*>(lp + row0*256 + e);
        const unsigned short* au = reinterpret_cast<const unsigned short*>(&ua);
        const unsigned short* bu = reinterpret_cast<const unsigned short*>(&ub);
        #pragma unroll
        for (int jj = 0; jj < 8; ++jj) as[e+jj] = bf2f(au[jj]) + bf2f(bu[jj]);
    }
    __syncthreads();
    float a[8];
    const float bv = ldin<F32>(bo, t);
    #pragma unroll
    for (int r = 0; r < 8; ++r) a[r] = bv;
    for (int i0 = 0; i0 < 256; i0 += 4) {
        float w0 = ldin<F32>(Wo, (i0+0)*256 + t);
        float w1 = ldin<F32>(Wo, (i0+1)*256 + t);
        float w2 = ldin<F32>(Wo, (i0+2)*256 + t);
        float w3 = ldin<F32>(Wo, (i0+3)*256 + t);
        #pragma unroll
        for (int r = 0; r < 8; ++r) {
            float4 xv = *reinterpret_cast<const float4*>(&as[r*256 + i0]);
            a[r] = fmaf(xv.w,w3, fmaf(xv.z,w2, fmaf(xv.y,w1, fmaf(xv.x,w0, a[r]))));
        }
    }
    #pragma unroll
    for (int r = 0; r < 8; ++r) {
        int idx = (row0+r)*256 + t;
        if constexpr (F32) ((float*)out)[idx] = a[r];
        else ((unsigned short*)out)[idx] = f2bf(a[r]);
    }
}

__global__ __launch_bounds__(256) void out_kernel(
    const unsigned short* __restrict__ o, const unsigned short* __restrict__ lp,
    const void* __restrict__ Wo, const void* __restrict__ bo,
    const int* __restrict__ flag, void* __restrict__ out)
{
    __shared__ float as[8*256];
    if (*flag) out_body<1>(o, lp, Wo, bo, out, as);
    else       out_body<0>(o, lp, Wo, bo, out, as);
}

extern "C" void kernel_launch(void* const* d_in, const int* in_sizes, int n_in,
                              void* d_out, int out_size, void* d_ws, size_t ws_size,
                              hipStream_t stream)
{
    const void* x  = d_in[0];
    const void* Wq = d_in[1];
    const void* bq = d_in[2];
    const void* Wk = d_in[3];
    const void* bk = d_in[4];
    const void* Wv = d_in[5];
    const void* bv = d_in[6];
    const void* lw = d_in[7];
    const void* lb = d_in[8];
    const void* Wo = d_in[9];
    const void* bo = d_in[10];

    // ws: [flag 256B][q][k][v][o][lp][vT] each SZ bf16 (2.36MB) = ~14.2MB
    int* flag = (int*)d_ws;
    unsigned short* qb   = (unsigned short*)((char*)d_ws + 256);
    unsigned short* kbuf = qb   + (size_t)SZ;
    unsigned short* vbuf = kbuf + (size_t)SZ;
    unsigned short* obuf = vbuf + (size_t)SZ;
    unsigned short* lbuf = obuf + (size_t)SZ;
    unsigned short* vtb  = lbuf + (size_t)SZ;

    detect_kernel<<<1, 64, 0, stream>>>((const unsigned int*)x, flag);
    qkv_kernel<<<dim3(288,3), 256, 0, stream>>>(x, Wq, bq, Wk, bk, Wv, bv, flag, qb, kbuf, vbuf, vtb);
    lepe_kernel<<<4608, 256, 0, stream>>>(vbuf, lw, lb, flag, lbuf);
    attn_kernel<<<dim3(36, 16), 256, 0, stream>>>(qb, kbuf, vtb, obuf);
    out_kernel<<<576, 256, 0, stream>>>(obuf, lbuf, Wo, bo, flag, d_out);
}

// Round 2
// 232.751 us; speedup vs baseline: 1.1759x; 1.1759x over previous
//
#include <hip/hip_runtime.h>
#include <hip/hip_bf16.h>
#include <math.h>

#define NN 2304      // H*W = 48*48
#define ROWSZ 4608   // B*N
#define SZ (ROWSZ*256)

typedef __attribute__((ext_vector_type(8))) short short8;
typedef __attribute__((ext_vector_type(4))) float f32x4;

__device__ __forceinline__ float bf2f(unsigned short u) {
    return __uint_as_float(((unsigned int)u) << 16);
}
__device__ __forceinline__ unsigned short f2bf(float f) {
    unsigned int u = __float_as_uint(f);
    u += 0x7FFFu + ((u >> 16) & 1u);   // round-to-nearest-even
    return (unsigned short)(u >> 16);
}
__device__ __forceinline__ unsigned int pack_bf2(float a, float b) {
    return (unsigned int)f2bf(a) | ((unsigned int)f2bf(b) << 16);
}

template<int F32>
__device__ __forceinline__ float ldin(const void* p, int i) {
    if constexpr (F32) return ((const float*)p)[i];
    else return bf2f(((const unsigned short*)p)[i]);
}

// ---------------- dtype detector -------------------------------------------
__global__ void detect_kernel(const unsigned int* __restrict__ x, int* __restrict__ flag) {
    int t = threadIdx.x;
    int cnt = 0;
    for (int i = t; i < 256; i += 64) {
        unsigned int e = (x[i] >> 7) & 0xFFu;
        cnt += (e < 87u || e > 167u) ? 1 : 0;
    }
    #pragma unroll
    for (int o = 32; o; o >>= 1) cnt += __shfl_down(cnt, o);
    if (t == 0) *flag = (cnt >= 32) ? 1 : 0;
}

// ---------------- QKV projection + fused RoPE + k-scaling + vT -------------
// grid (288,3): 16 rows/block, blockIdx.y selects matrix {q,k,v}
template<int F32>
__device__ __forceinline__ void qkv_body(
    const void* __restrict__ x,
    const void* __restrict__ Wq, const void* __restrict__ bq,
    const void* __restrict__ Wk, const void* __restrict__ bk,
    const void* __restrict__ Wv, const void* __restrict__ bv,
    unsigned short* __restrict__ q, unsigned short* __restrict__ k,
    unsigned short* __restrict__ v, unsigned short* __restrict__ vT,
    float* __restrict__ xs)
{
    const int t = threadIdx.x;
    const int by = blockIdx.y;
    const int row0 = blockIdx.x * 16;
    #pragma unroll
    for (int pass = 0; pass < 2; ++pass) {
        int e = pass*2048 + t*8;
        if constexpr (F32) {
            const float* xp = (const float*)x + row0*256 + e;
            float4 a0 = *reinterpret_cast<const float4*>(xp);
            float4 a1 = *reinterpret_cast<const float4*>(xp + 4);
            *reinterpret_cast<float4*>(&xs[e])   = a0;
            *reinterpret_cast<float4*>(&xs[e+4]) = a1;
        } else {
            const unsigned short* xp = (const unsigned short*)x + row0*256 + e;
            uint4 raw = *reinterpret_cast<const uint4*>(xp);
            const unsigned short* us = reinterpret_cast<const unsigned short*>(&raw);
            #pragma unroll
            for (int j = 0; j < 8; ++j) xs[e + j] = bf2f(us[j]);
        }
    }
    __syncthreads();
    const void* Wsel = (by == 0) ? Wq : (by == 1) ? Wk : Wv;
    const void* bsel = (by == 0) ? bq : (by == 1) ? bk : bv;
    float a[16];
    const float bv0 = ldin<F32>(bsel, t);
    #pragma unroll
    for (int r = 0; r < 16; ++r) a[r] = bv0;
    for (int i0 = 0; i0 < 256; i0 += 4) {
        float w0 = ldin<F32>(Wsel, (i0+0)*256 + t);
        float w1 = ldin<F32>(Wsel, (i0+1)*256 + t);
        float w2 = ldin<F32>(Wsel, (i0+2)*256 + t);
        float w3 = ldin<F32>(Wsel, (i0+3)*256 + t);
        #pragma unroll
        for (int r = 0; r < 16; ++r) {
            float4 xv = *reinterpret_cast<const float4*>(&xs[r*256 + i0]);
            a[r] = fmaf(xv.w,w3, fmaf(xv.z,w2, fmaf(xv.y,w1, fmaf(xv.x,w0, a[r]))));
        }
    }
    if (by == 2) {
        // v row-major + vT [bh][d][n]
        const int b = (row0 >= NN) ? 1 : 0;
        const int n0 = row0 - b*NN;
        const int h = t >> 5, d = t & 31;
        unsigned int vp[8];
        #pragma unroll
        for (int r = 0; r < 16; ++r) v[(row0 + r)*256 + t] = f2bf(a[r]);
        #pragma unroll
        for (int r = 0; r < 8; ++r) vp[r] = pack_bf2(a[2*r], a[2*r+1]);
        unsigned short* vt = vT + ((size_t)(b*8 + h)*32 + d)*NN + n0;
        *reinterpret_cast<uint4*>(vt)     = make_uint4(vp[0], vp[1], vp[2], vp[3]);
        *reinterpret_cast<uint4*>(vt + 8) = make_uint4(vp[4], vp[5], vp[6], vp[7]);
    } else {
        // RoPE: column t -> pair j=(t&31)>>1
        const float scaling = 0.17677669529663687f;  // 32^-0.5
        const int j = (t & 31) >> 1;
        const float ang = exp2f((float)j * (-0.8858474919699633f)); // 10000^(-j/15)
        const bool odd = t & 1;
        unsigned short* dst = (by == 0) ? q : k;
        const float mul = (by == 0) ? 1.0f : scaling;
        #pragma unroll
        for (int r = 0; r < 16; ++r) {
            int bn = row0 + r;
            int n = bn >= NN ? bn - NN : bn;
            float sv, cv;
            sincosf((float)n * ang, &sv, &cv);
            float ap = __shfl_xor(a[r], 1);
            float val = odd ? fmaf(a[r], cv, ap*sv) : fmaf(a[r], cv, -ap*sv);
            dst[bn*256 + t] = f2bf(val * mul);
        }
    }
}

__global__ __launch_bounds__(256) void qkv_kernel(
    const void* __restrict__ x,
    const void* __restrict__ Wq, const void* __restrict__ bq,
    const void* __restrict__ Wk, const void* __restrict__ bk,
    const void* __restrict__ Wv, const void* __restrict__ bv,
    const int* __restrict__ flag,
    unsigned short* __restrict__ q, unsigned short* __restrict__ k,
    unsigned short* __restrict__ v, unsigned short* __restrict__ vT)
{
    __shared__ float xs[16*256];
    if (*flag) qkv_body<1>(x, Wq, bq, Wk, bk, Wv, bv, q, k, v, vT, xs);
    else       qkv_body<0>(x, Wq, bq, Wk, bk, Wv, bv, q, k, v, vT, xs);
}

// ---------------- depthwise 5x5 SAME conv on v (+ bias) --------------------
template<int F32>
__device__ __forceinline__ void lepe_body(const unsigned short* __restrict__ v,
    const void* __restrict__ w, const void* __restrict__ wb,
    unsigned short* __restrict__ lepe)
{
    int c = threadIdx.x;
    int pos = blockIdx.x;                // b*2304 + y*48 + x
    int b  = pos >= NN ? 1 : 0;
    int yx = pos - b*NN;
    int y  = (yx*21846) >> 20;           // yx/48 exact
    int xx = yx - y*48;
    float acc = ldin<F32>(wb, c);
    #pragma unroll
    for (int ky = 0; ky < 5; ++ky) {
        int yy = y + ky - 2;
        if ((unsigned)yy >= 48u) continue;
        #pragma unroll
        for (int kx = 0; kx < 5; ++kx) {
            int xc = xx + kx - 2;
            if ((unsigned)xc >= 48u) continue;
            acc = fmaf(bf2f(v[((b*NN + yy*48 + xc)<<8) + c]), ldin<F32>(w, c*25 + ky*5 + kx), acc);
        }
    }
    lepe[(pos<<8) + c] = f2bf(acc);
}

__global__ __launch_bounds__(256) void lepe_kernel(const unsigned short* __restrict__ v,
    const void* __restrict__ w, const void* __restrict__ wb,
    const int* __restrict__ flag, unsigned short* __restrict__ lepe)
{
    if (*flag) lepe_body<1>(v, w, wb, lepe);
    else       lepe_body<0>(v, w, wb, lepe);
}

// ---------------- MFMA flash attention with decay mask ---------------------
// grid (36,16,nsplit), 256 thr = 4 waves; wave w: 16 q-rows; chunk = 64 kpos.
// LDS-staged K/Vt (round-0 proven inner loop). Fixed-max softmax (scores
// bounded ~1, mask <= 0): partitions over K are linearly composable, so
// blockIdx.z processes 36/nsplit chunks and writes unnormalized f32 O^T
// partials + l. DIRECT=1 (nsplit==1 fallback): normalize+write bf16 directly.
// S^T tiles: A=K (m=kpos), B=Q^T (n=q); PV: O^T = Vt * P^T.
template<int DIRECT>
__global__ __launch_bounds__(256) void attn_kernel(
    const unsigned short* __restrict__ q, const unsigned short* __restrict__ k,
    const unsigned short* __restrict__ vT, unsigned short* __restrict__ o,
    float* __restrict__ pacc, float* __restrict__ pl)
{
    __shared__ char smem[17920];
    char* KsB = smem;                 // 64 rows * 80B (32 bf16 + pad)
    char* VtB = smem + 5120;          // 32 rows * 144B (64 bf16 + pad)
    const int t = threadIdx.x;
    const int w = t >> 6, lane = t & 63;
    const int q16 = lane & 15, quad = lane >> 4;
    char* PsB = smem + 9728 + w*2048; // per-wave P scratch, frag-ordered (2*1024B)
    const int bh = blockIdx.y, b = bh >> 3, h = bh & 7;
    const int q0 = blockIdx.x*64 + w*16;
    const int nq = q0 + q16;
    const int yq = (nq*21846) >> 20, xq = nq - yq*48;
    const float decay = logf(1.0f - exp2f(-1.0f - 0.375f*(float)h));
    short8 qfrag = *reinterpret_cast<const short8*>(q + ((size_t)(b*NN + nq))*256 + h*32 + quad*8);
    f32x4 acc0 = {0.f,0.f,0.f,0.f}, acc1 = {0.f,0.f,0.f,0.f};
    const f32x4 zero = {0.f,0.f,0.f,0.f};
    float lacc = 0.0f;
    const unsigned short* kbase = k + (size_t)(b*NN)*256 + h*32;
    const unsigned short* vtb = vT + (size_t)bh*32*NN;
    const int skr = t >> 2, skp = t & 3;      // K staging: row, 16B-part
    const int svd = t >> 3, svp = t & 7;      // Vt staging: d, 16B-part
    const int psW = q16*16 + (quad & 1)*8;    // P write base within group
    const int qsh = quad >> 1;
    const int nchunk = 36 / gridDim.z;
    const int kt0 = blockIdx.z * nchunk;
    for (int kc = 0; kc < nchunk; ++kc) {
        const int kt = kt0 + kc;
        __syncthreads();
        {
            uint4 kraw = *reinterpret_cast<const uint4*>(kbase + (kt*64 + skr)*256 + skp*8);
            uint4 vraw = *reinterpret_cast<const uint4*>(vtb + svd*NN + kt*64 + svp*8);
            *reinterpret_cast<uint4*>(KsB + skr*80 + skp*16) = kraw;
            *reinterpret_cast<uint4*>(VtB + svd*144 + svp*16) = vraw;
        }
        __syncthreads();
        // QK^T: 4 S^T tiles of [16 kpos x 16 q]
        f32x4 st[4];
        #pragma unroll
        for (int tt = 0; tt < 4; ++tt) {
            short8 kf = *reinterpret_cast<const short8*>(KsB + (tt*16 + q16)*80 + quad*16);
            st[tt] = __builtin_amdgcn_mfma_f32_16x16x32_bf16(kf, qfrag, zero, 0, 0, 0);
        }
        // decay mask + exp (fixed max = 0), pack to bf16 pairs
        unsigned int pk[8];
        float lsum = 0.0f;
        #pragma unroll
        for (int tt = 0; tt < 4; ++tt) {
            float p[4];
            #pragma unroll
            for (int r = 0; r < 4; ++r) {
                int kpos = kt*64 + tt*16 + quad*4 + r;
                int yk = (kpos*21846) >> 20;
                int xk = kpos - yk*48;
                int dist = __usad((unsigned)yq, (unsigned)yk, __usad((unsigned)xq, (unsigned)xk, 0u));
                p[r] = __expf(fmaf(decay, (float)dist, st[tt][r]));
                lsum += p[r];
            }
            pk[tt*2]   = __builtin_amdgcn_perm(__float_as_uint(p[1]), __float_as_uint(p[0]), 0x07060302);
            pk[tt*2+1] = __builtin_amdgcn_perm(__float_as_uint(p[3]), __float_as_uint(p[2]), 0x07060302);
        }
        lacc += lsum;
        // P -> LDS (frag order): value(q16, kp=tt*16+quad*4+r) at
        //   [kh=tt>>1][quadT=(tt*2+qsh)&3][q16][j=(quad&1)*4+r]
        #pragma unroll
        for (int tt = 0; tt < 4; ++tt) {
            uint2 pp; pp.x = pk[tt*2]; pp.y = pk[tt*2+1];
            *reinterpret_cast<uint2*>(PsB + (tt >> 1)*1024 + (((tt*2) + qsh) & 3)*256 + psW) = pp;
        }
        // PV: O^T += Vt * P^T  (two 32-kpos steps, two 16-d tiles)
        #pragma unroll
        for (int kh = 0; kh < 2; ++kh) {
            short8 pf = *reinterpret_cast<const short8*>(PsB + kh*1024 + lane*16);
            short8 v0 = *reinterpret_cast<const short8*>(VtB + q16*144 + kh*64 + quad*16);
            short8 v1 = *reinterpret_cast<const short8*>(VtB + (16 + q16)*144 + kh*64 + quad*16);
            acc0 = __builtin_amdgcn_mfma_f32_16x16x32_bf16(v0, pf, acc0, 0, 0, 0);
            acc1 = __builtin_amdgcn_mfma_f32_16x16x32_bf16(v1, pf, acc1, 0, 0, 0);
        }
    }
    // l reduction across quads
    lacc += __shfl_xor(lacc, 16);
    lacc += __shfl_xor(lacc, 32);
    if constexpr (DIRECT) {
        float invl = 1.0f / lacc;
        // lane holds O^T[d = half*16 + quad*4 + r][q = nq]
        unsigned short* orow = o + ((size_t)(b*NN + nq))*256 + h*32;
        uint2 w0, w1;
        w0.x = pack_bf2(acc0[0]*invl, acc0[1]*invl);
        w0.y = pack_bf2(acc0[2]*invl, acc0[3]*invl);
        w1.x = pack_bf2(acc1[0]*invl, acc1[1]*invl);
        w1.y = pack_bf2(acc1[2]*invl, acc1[3]*invl);
        *reinterpret_cast<uint2*>(orow + quad*4)      = w0;
        *reinterpret_cast<uint2*>(orow + 16 + quad*4) = w1;
    } else {
        // unnormalized partial: pacc[part][bh][nq][32d] f32, pl[part][bh][nq]
        float* pb = pacc + ((size_t)(blockIdx.z*16 + bh)*NN + nq)*32;
        *reinterpret_cast<f32x4*>(pb + quad*4)      = acc0;
        *reinterpret_cast<f32x4*>(pb + 16 + quad*4) = acc1;
        if (quad == 0) pl[((size_t)blockIdx.z*16 + bh)*NN + nq] = lacc;
    }
}

// ---------------- reduce partials + lepe, then @ Wo + bo -> out ------------
// grid 576: 8 rows/block. nsplit==0: read bf16 o directly (DIRECT attn path).
template<int F32>
__device__ __forceinline__ void out_body(
    const unsigned short* __restrict__ o,
    const float* __restrict__ pacc, const float* __restrict__ pl,
    const unsigned short* __restrict__ lp,
    const void* __restrict__ Wo, const void* __restrict__ bo,
    void* __restrict__ out, float* __restrict__ as, int nsplit)
{
    const int t = threadIdx.x;
    const int row0 = blockIdx.x * 8;
    {
        const int e = t*8;                 // elem within 8x256 tile
        const int r = t >> 5;              // row in tile
        const int nqr = row0 + r;          // global row (b*NN + n)
        const int ch = e & 255;            // channel (multiple of 8)
        uint4 ub = *reinterpret_cast<const uint4*>(lp + nqr*256 + ch);
        const unsigned short* bu = reinterpret_cast<const unsigned short*>(&ub);
        if (nsplit == 0) {
            uint4 ua = *reinterpret_cast<const uint4*>(o + nqr*256 + ch);
            const unsigned short* au = reinterpret_cast<const unsigned short*>(&ua);
            #pragma unroll
            for (int jj = 0; jj < 8; ++jj) as[e+jj] = bf2f(au[jj]) + bf2f(bu[jj]);
        } else {
            const int b = nqr >= NN ? 1 : 0;
            const int nq = nqr - b*NN;
            const int h = ch >> 5, d = ch & 31;   // d in {0,8,16,24}
            const int bh = b*8 + h;
            float s[8] = {0.f,0.f,0.f,0.f,0.f,0.f,0.f,0.f};
            float lsum = 0.0f;
            for (int p = 0; p < nsplit; ++p) {
                const float* pb = pacc + ((size_t)(p*16 + bh)*NN + nq)*32 + d;
                f32x4 v0 = *reinterpret_cast<const f32x4*>(pb);
                f32x4 v1 = *reinterpret_cast<const f32x4*>(pb + 4);
                #pragma unroll
                for (int jj = 0; jj < 4; ++jj) { s[jj] += v0[jj]; s[4+jj] += v1[jj]; }
                lsum += pl[((size_t)p*16 + bh)*NN + nq];
            }
            float invl = 1.0f / lsum;
            #pragma unroll
            for (int jj = 0; jj < 8; ++jj) as[e+jj] = fmaf(s[jj], invl, bf2f(bu[jj]));
        }
    }
    __syncthreads();
    float a[8];
    const float bv = ldin<F32>(bo, t);
    #pragma unroll
    for (int r = 0; r < 8; ++r) a[r] = bv;
    for (int i0 = 0; i0 < 256; i0 += 4) {
        float w0 = ldin<F32>(Wo, (i0+0)*256 + t);
        float w1 = ldin<F32>(Wo, (i0+1)*256 + t);
        float w2 = ldin<F32>(Wo, (i0+2)*256 + t);
        float w3 = ldin<F32>(Wo, (i0+3)*256 + t);
        #pragma unroll
        for (int r = 0; r < 8; ++r) {
            float4 xv = *reinterpret_cast<const float4*>(&as[r*256 + i0]);
            a[r] = fmaf(xv.w,w3, fmaf(xv.z,w2, fmaf(xv.y,w1, fmaf(xv.x,w0, a[r]))));
        }
    }
    #pragma unroll
    for (int r = 0; r < 8; ++r) {
        int idx = (row0+r)*256 + t;
        if constexpr (F32) ((float*)out)[idx] = a[r];
        else ((unsigned short*)out)[idx] = f2bf(a[r]);
    }
}

__global__ __launch_bounds__(256) void out_kernel(
    const unsigned short* __restrict__ o,
    const float* __restrict__ pacc, const float* __restrict__ pl,
    const unsigned short* __restrict__ lp,
    const void* __restrict__ Wo, const void* __restrict__ bo,
    const int* __restrict__ flag, void* __restrict__ out, int nsplit)
{
    __shared__ float as[8*256];
    if (*flag) out_body<1>(o, pacc, pl, lp, Wo, bo, out, as, nsplit);
    else       out_body<0>(o, pacc, pl, lp, Wo, bo, out, as, nsplit);
}

extern "C" void kernel_launch(void* const* d_in, const int* in_sizes, int n_in,
                              void* d_out, int out_size, void* d_ws, size_t ws_size,
                              hipStream_t stream)
{
    const void* x  = d_in[0];
    const void* Wq = d_in[1];
    const void* bq = d_in[2];
    const void* Wk = d_in[3];
    const void* bk = d_in[4];
    const void* Wv = d_in[5];
    const void* bv = d_in[6];
    const void* lw = d_in[7];
    const void* lb = d_in[8];
    const void* Wo = d_in[9];
    const void* bo = d_in[10];

    // ws: [flag 256B][q][k][v][o][lp][vT] each SZ bf16 (~14.2MB), then
    //     [pacc: nsplit*16*NN*32 f32][pl: nsplit*16*NN f32]
    int* flag = (int*)d_ws;
    unsigned short* qb   = (unsigned short*)((char*)d_ws + 256);
    unsigned short* kbuf = qb   + (size_t)SZ;
    unsigned short* vbuf = kbuf + (size_t)SZ;
    unsigned short* obuf = vbuf + (size_t)SZ;
    unsigned short* lbuf = obuf + (size_t)SZ;
    unsigned short* vtb  = lbuf + (size_t)SZ;

    const size_t base = 256 + 6*(size_t)SZ*2;
    const size_t per_split = (size_t)16*NN*32*4 + (size_t)16*NN*4;  // pacc + pl
    int nsplit = 0;
    if      (ws_size >= base + 4*per_split) nsplit = 4;
    else if (ws_size >= base + 2*per_split) nsplit = 2;
    else if (ws_size >= base + 1*per_split) nsplit = 1;
    float* pacc = (float*)((char*)d_ws + base);
    float* pl   = pacc + (size_t)(nsplit ? nsplit : 1)*16*NN*32;

    detect_kernel<<<1, 64, 0, stream>>>((const unsigned int*)x, flag);
    qkv_kernel<<<dim3(288,3), 256, 0, stream>>>(x, Wq, bq, Wk, bk, Wv, bv, flag, qb, kbuf, vbuf, vtb);
    lepe_kernel<<<4608, 256, 0, stream>>>(vbuf, lw, lb, flag, lbuf);
    if (nsplit) {
        attn_kernel<0><<<dim3(36, 16, nsplit), 256, 0, stream>>>(qb, kbuf, vtb, obuf, pacc, pl);
    } else {
        attn_kernel<1><<<dim3(36, 16, 1), 256, 0, stream>>>(qb, kbuf, vtb, obuf, pacc, pl);
    }
    out_kernel<<<576, 256, 0, stream>>>(obuf, pacc, pl, lbuf, Wo, bo, flag, d_out, nsplit);
}